// Round 1
// baseline (341.161 us; speedup 1.0000x reference)
//
#include <hip/hip_runtime.h>
#include <hip/hip_bf16.h>

typedef __attribute__((ext_vector_type(8))) short bf16x8;
typedef __attribute__((ext_vector_type(4))) short bf16x4;
typedef __attribute__((ext_vector_type(4))) float f32x4;

#define N_PTS (1u<<20)
#define RES 512
#define ED 256
#define HID 128
#define NOUT 3
#define W0F 30.0f
#define MT 64                 // points per tile
#define NTILES (N_PTS/MT)     // 16384
#define EST 264               // e_tile stride in bf16 (256 + 8 pad, keeps 16B align)
#define HST 136               // h_tile stride in bf16 (128 + 8 pad)

__device__ __forceinline__ short f2bf(float f) {
  union { float f; unsigned u; } v; v.f = f;
  unsigned r = v.u + 0x7fffu + ((v.u >> 16) & 1u);   // round-to-nearest-even
  return (short)(r >> 16);
}

__global__ __launch_bounds__(512, 4) void axisnet_kernel(
    const float* __restrict__ coords,
    const float* __restrict__ emb0,
    const float* __restrict__ emb1,
    const float* __restrict__ w0,
    const float* __restrict__ b0,
    const float* __restrict__ w1,
    const float* __restrict__ b1,
    const float* __restrict__ w2,
    const float* __restrict__ b2,
    float* __restrict__ out)
{
  __shared__ short e_tile[MT][EST];   // 33792 B
  __shared__ short h_tile[MT][HST];   // 17408 B

  const int tid  = threadIdx.x;
  const int lane = tid & 63;
  const int wv   = tid >> 6;      // wave 0..7
  const int g    = lane >> 4;     // k-group 0..3
  const int lr   = lane & 15;

  // Wave wv owns output columns 16*wv .. 16*wv+15 for layers 0 and 1.
  const int ncol = 16*wv + lr;

  // ---- persistent bf16 B-fragments (loaded once per block) ----
  // B layout for mfma_f32_16x16x32_bf16: lane supplies B[k][col], col=lane&15,
  // k = 32*ks + 8*(lane>>4) + j  -> contiguous k comes from w[col][k] row-major.
  bf16x8 w0f[8];
#pragma unroll
  for (int ks = 0; ks < 8; ++ks) {
    const float* p = w0 + ncol*ED + 32*ks + 8*g;
#pragma unroll
    for (int j = 0; j < 8; ++j) w0f[ks][j] = f2bf(p[j]);
  }
  bf16x8 w1f[4];
#pragma unroll
  for (int ks = 0; ks < 4; ++ks) {
    const float* p = w1 + ncol*HID + 32*ks + 8*g;
#pragma unroll
    for (int j = 0; j < 8; ++j) w1f[ks][j] = f2bf(p[j]);
  }
  const float b0v = b0[ncol];
  const float b1v = b1[ncol];
  const float b2v = (lr < NOUT) ? b2[lr] : 0.f;

  for (int tile = blockIdx.x; tile < (int)NTILES; tile += gridDim.x) {
    const int base = tile * MT;

    // ---------- gather + lerp: wave wv handles points base+8*wv .. +7 ----------
    const float2 cp = ((const float2*)coords)[base + 8*wv + (lane & 7)];
#pragma unroll 2
    for (int i = 0; i < 8; ++i) {
      float c0 = __shfl(cp.x, i);
      float c1 = __shfl(cp.y, i);
      c0 = fminf(fmaxf(c0, -1.f), 0.999f);
      c1 = fminf(fmaxf(c1, -1.f), 0.999f);
      float a0f = (0.5f*c0 + 0.5f) * (float)(RES-1);
      float a1f = (0.5f*c1 + 0.5f) * (float)(RES-1);
      int i0 = (int)a0f;             // a0f >= 0 so trunc == floor
      int i1 = (int)a1f;
      float wa = a0f - (float)i0;
      float wb = a1f - (float)i1;
      const f32x4* r0 = (const f32x4*)(emb0 + i0*ED) + lane;
      const f32x4* s0 = (const f32x4*)(emb1 + i1*ED) + lane;
      f32x4 x0 = r0[0], x1 = r0[ED/4], y0 = s0[0], y1 = s0[ED/4];
      bf16x4 ev;
#pragma unroll
      for (int j = 0; j < 4; ++j) {
        float ea = x0[j] + wa*(x1[j]-x0[j]);
        float eb = y0[j] + wb*(y1[j]-y0[j]);
        ev[j] = f2bf(ea*eb);
      }
      *(bf16x4*)&e_tile[8*wv + i][4*lane] = ev;   // lane covers k = 4*lane..+3
    }
    __syncthreads();

    // ---------- layer 0: [64x256] @ [256x128] ----------
    f32x4 acc0[4];
#pragma unroll
    for (int mt = 0; mt < 4; ++mt) acc0[mt] = (f32x4)0.f;
#pragma unroll
    for (int ks = 0; ks < 8; ++ks) {
#pragma unroll
      for (int mt = 0; mt < 4; ++mt) {
        bf16x8 a = *(const bf16x8*)&e_tile[16*mt + lr][32*ks + 8*g];
        acc0[mt] = __builtin_amdgcn_mfma_f32_16x16x32_bf16(a, w0f[ks], acc0[mt], 0, 0, 0);
      }
    }
    // epilogue: sin(30*(x+b)), write h_tile. C layout: row=(lane>>4)*4+r, col=lane&15.
#pragma unroll
    for (int mt = 0; mt < 4; ++mt) {
#pragma unroll
      for (int r = 0; r < 4; ++r) {
        float h = __sinf(W0F * (acc0[mt][r] + b0v));
        h_tile[16*mt + 4*g + r][16*wv + lr] = f2bf(h);
      }
    }
    __syncthreads();

    // ---------- layer 1: [64x128] @ [128x128] ----------
    f32x4 acc1[4];
#pragma unroll
    for (int mt = 0; mt < 4; ++mt) acc1[mt] = (f32x4)0.f;
#pragma unroll
    for (int ks = 0; ks < 4; ++ks) {
#pragma unroll
      for (int mt = 0; mt < 4; ++mt) {
        bf16x8 a = *(const bf16x8*)&h_tile[16*mt + lr][32*ks + 8*g];
        acc1[mt] = __builtin_amdgcn_mfma_f32_16x16x32_bf16(a, w1f[ks], acc1[mt], 0, 0, 0);
      }
    }
    __syncthreads();   // all h_tile reads done before overwrite with h2
#pragma unroll
    for (int mt = 0; mt < 4; ++mt) {
#pragma unroll
      for (int r = 0; r < 4; ++r) {
        float h = __sinf(W0F * (acc1[mt][r] + b1v));
        h_tile[16*mt + 4*g + r][16*wv + lr] = f2bf(h);
      }
    }
    __syncthreads();

    // ---------- layer 2: [64x128] @ [128x3] (padded to 16 cols), waves 0..3 ----------
    if (wv < 4) {
      f32x4 acc2 = (f32x4)0.f;
#pragma unroll
      for (int ks = 0; ks < 4; ++ks) {
        bf16x8 bfrag;
        if (lr < NOUT) {
          const float* p = w2 + lr*HID + 32*ks + 8*g;
#pragma unroll
          for (int j = 0; j < 8; ++j) bfrag[j] = f2bf(p[j]);
        } else {
          bfrag = (bf16x8)0;
        }
        bf16x8 a = *(const bf16x8*)&h_tile[16*wv + lr][32*ks + 8*g];
        acc2 = __builtin_amdgcn_mfma_f32_16x16x32_bf16(a, bfrag, acc2, 0, 0, 0);
      }
      if (lr < NOUT) {
#pragma unroll
        for (int r = 0; r < 4; ++r) {
          int pt = base + 16*wv + 4*g + r;
          out[pt*3 + lr] = acc2[r] + b2v;
        }
      }
    }
  }
}

extern "C" void kernel_launch(void* const* d_in, const int* in_sizes, int n_in,
                              void* d_out, int out_size, void* d_ws, size_t ws_size,
                              hipStream_t stream) {
  const float* coords = (const float*)d_in[0];
  const float* emb0   = (const float*)d_in[1];
  const float* emb1   = (const float*)d_in[2];
  const float* w0     = (const float*)d_in[3];
  const float* b0     = (const float*)d_in[4];
  const float* w1     = (const float*)d_in[5];
  const float* b1     = (const float*)d_in[6];
  const float* w2     = (const float*)d_in[7];
  const float* b2     = (const float*)d_in[8];
  float* out = (float*)d_out;

  dim3 grid(512), block(512);
  hipLaunchKernelGGL(axisnet_kernel, grid, block, 0, stream,
                     coords, emb0, emb1, w0, b0, w1, b1, w2, b2, out);
}